// Round 3
// baseline (950.988 us; speedup 1.0000x reference)
//
#include <hip/hip_runtime.h>
#include <stdint.h>

typedef unsigned short ushort_t;
typedef uint32_t u32;
typedef __bf16 bf16;
typedef bf16 bf16x8 __attribute__((ext_vector_type(8)));
typedef float f32x4 __attribute__((ext_vector_type(4)));
typedef ushort_t ushort8 __attribute__((ext_vector_type(8)));

__device__ __forceinline__ float b2f(ushort_t u) {
    u32 x = ((u32)u) << 16;
    return __builtin_bit_cast(float, x);
}
__device__ __forceinline__ ushort_t f2b(float f) {
    bf16 h = (bf16)f;
    return __builtin_bit_cast(ushort_t, h);
}
__device__ __forceinline__ float sigmoidf_(float x) { return 1.0f / (1.0f + __expf(-x)); }
__device__ __forceinline__ float tanhf_(float x) { return 1.0f - 2.0f / (1.0f + __expf(2.0f * x)); }

// load 8 consecutive fp32, round-to-nearest to bf16, return packed ushort8
__device__ __forceinline__ ushort8 cvt8(const float* __restrict__ p) {
    float4 v0 = *(const float4*)p;
    float4 v1 = *(const float4*)(p + 4);
    ushort8 r;
    r[0] = f2b(v0.x); r[1] = f2b(v0.y); r[2] = f2b(v0.z); r[3] = f2b(v0.w);
    r[4] = f2b(v1.x); r[5] = f2b(v1.y); r[6] = f2b(v1.z); r[7] = f2b(v1.w);
    return r;
}

// ---------------------------------------------------------------------------
// GEMM: C[M][1536] = A[M][K] @ [WF;WB]^T + [bF;bB]  (A,W,b fp32; C bf16).
// A row optionally gathered via tokens. 128x128 tile, 256 thr, bf16 MFMA.
// ---------------------------------------------------------------------------
#define TPAD 40  // LDS tile row stride (bf16): 32 data + 8 pad

__global__ __launch_bounds__(256) void gemm_xg(
    const float* __restrict__ A, const int* __restrict__ tok,
    const float* __restrict__ WF, const float* __restrict__ WB,
    const float* __restrict__ bF, const float* __restrict__ bB,
    ushort_t* __restrict__ C, int K)
{
    __shared__ ushort_t aT[128 * TPAD];
    __shared__ ushort_t bT[128 * TPAD];
    const int tid = threadIdx.x;
    const int lane = tid & 63, wv = tid >> 6;
    const int bn0 = blockIdx.x * 128;
    const int rm0 = blockIdx.y * 128;
    const int wm = (wv & 1) * 64, wn = (wv >> 1) * 64;

    f32x4 acc[4][4];
    f32x4 zero = {0.f, 0.f, 0.f, 0.f};
#pragma unroll
    for (int i = 0; i < 4; i++)
#pragma unroll
        for (int j = 0; j < 4; j++) acc[i][j] = zero;

    const int sr = tid >> 1;          // staged row 0..127
    const int sk = (tid & 1) * 16;    // k offset 0/16
    long arow = tok ? (long)tok[rm0 + sr] : (long)(rm0 + sr);
    const float* aSrc = A + arow * K + sk;
    int ng = bn0 + sr;
    const float* bSrc = (ng < 768 ? WF + (long)ng * K : WB + (long)(ng - 768) * K) + sk;

    const int nkc = K / 32;
    const int fm = lane & 15, fq = (lane >> 4) * 8;
    for (int kc = 0; kc < nkc; ++kc) {
        ushort8 av0 = cvt8(aSrc + kc * 32);
        ushort8 av1 = cvt8(aSrc + kc * 32 + 8);
        ushort8 bv0 = cvt8(bSrc + kc * 32);
        ushort8 bv1 = cvt8(bSrc + kc * 32 + 8);
        __syncthreads();
        *(ushort8*)(aT + sr * TPAD + sk) = av0;
        *(ushort8*)(aT + sr * TPAD + sk + 8) = av1;
        *(ushort8*)(bT + sr * TPAD + sk) = bv0;
        *(ushort8*)(bT + sr * TPAD + sk + 8) = bv1;
        __syncthreads();
        bf16x8 af[4], bfg[4];
#pragma unroll
        for (int i = 0; i < 4; i++)
            af[i] = __builtin_bit_cast(bf16x8, *(const ushort8*)(aT + (wm + i * 16 + fm) * TPAD + fq));
#pragma unroll
        for (int j = 0; j < 4; j++)
            bfg[j] = __builtin_bit_cast(bf16x8, *(const ushort8*)(bT + (wn + j * 16 + fm) * TPAD + fq));
#pragma unroll
        for (int i = 0; i < 4; i++)
#pragma unroll
            for (int j = 0; j < 4; j++)
                acc[i][j] = __builtin_amdgcn_mfma_f32_16x16x32_bf16(af[i], bfg[j], acc[i][j], 0, 0, 0);
    }
    const int fr0 = (lane >> 4) * 4;
#pragma unroll
    for (int j = 0; j < 4; j++) {
        int col = bn0 + wn + j * 16 + fm;
        float bias = (col < 768) ? bF[col] : bB[col - 768];
#pragma unroll
        for (int i = 0; i < 4; i++) {
#pragma unroll
            for (int r = 0; r < 4; r++) {
                int row = rm0 + wm + i * 16 + fr0 + r;
                C[(long)row * 1536 + col] = f2b(acc[i][j][r] + bias);
            }
        }
    }
}

// ---------------------------------------------------------------------------
// Register-persistent bi-GRU, v2: in-wave gate math, 1 barrier/step.
// 512 threads = 8 waves. Wave w owns h-dims [32w,32w+32) and holds the r/z/n
// gate rows for those dims as 6 16-row MFMA B-tiles (192 VGPR).
// After MFMA, pre-activations for dims 32w+16t+(lane&15), sentence m, live in
// acc[g*2+t][m] of lanes 0..15 (C layout row=(lane>>4)*4+reg). Gate
// nonlinearity is computed in-wave (no LDS round-trip, no mid-step barrier).
// h state: fp32 regs (lanes 0..15); bf16 copy in double-buffered LDS for the
// next step's A-fragments. x(t+1) prefetched into regs; out store deferred
// one step so it drains under MFMA, not at the barrier.
// grid = 2 * (nSent/NS); blockIdx&1 = direction. PyTorch gate order r,z,n.
// ---------------------------------------------------------------------------
#define HBS 264   // hbf row stride (bf16): 256 + 8 pad

template<int NS>
__global__ __launch_bounds__(512, 2) void gru_level(
    const float* __restrict__ WhhF, const float* __restrict__ WhhB,
    const float* __restrict__ bhhF, const float* __restrict__ bhhB,
    const ushort_t* __restrict__ xg,   // [nSent*T][1536] bf16 (F cols 0..767, B 768..1535)
    ushort_t* __restrict__ out,        // [nSent*T][512] bf16 (F dims 0..255, B 256..511)
    int T)
{
    __shared__ ushort_t hbf[2][16 * HBS];

    const int tid = threadIdx.x, lane = tid & 63, wv = tid >> 6;
    const int dir = blockIdx.x & 1;
    const int grp = blockIdx.x >> 1;
    const float* Whh = dir ? WhhB : WhhF;
    const float* bhh = dir ? bhhB : bhhF;
    const int dirOff = dir * 768;

    const int fm = lane & 15, fq = (lane >> 4) * 8;
    const int mgrp = lane >> 4;
    const int d0 = 32 * wv + fm;       // t=0 dim owned by this lane; t=1 is +16

    // persistent weights: tile (g,t) covers gate-rows g*256 + 32w + 16t .. +16
    bf16x8 wfrag[6][8];
#pragma unroll
    for (int g = 0; g < 3; ++g)
#pragma unroll
        for (int t = 0; t < 2; ++t) {
            const float* wrow = Whh + (long)(g * 256 + 32 * wv + 16 * t + fm) * 256 + fq;
#pragma unroll
            for (int kc = 0; kc < 8; ++kc)
                wfrag[g * 2 + t][kc] = __builtin_bit_cast(bf16x8, cvt8(wrow + kc * 32));
        }

    float bhhv[3][2];
#pragma unroll
    for (int g = 0; g < 3; ++g)
#pragma unroll
        for (int t = 0; t < 2; ++t)
            bhhv[g][t] = bhh[g * 256 + d0 + 16 * t];

    // zero both h buffers (rows >= NS stay zero forever)
    for (int i = tid; i < 16 * HBS; i += 512) { hbf[0][i] = 0; hbf[1][i] = 0; }

    const ushort_t* xgm[NS];
    ushort_t* outm[NS];
#pragma unroll
    for (int m = 0; m < NS; ++m) {
        int s = grp * NS + m;
        xgm[m] = xg + (long)s * T * 1536 + dirOff;
        outm[m] = out + (long)s * T * 512 + dir * 256;
    }

    float h[NS][2];
    ushort_t xv[NS][3][2];
    ushort_t ostage[NS][2];
#pragma unroll
    for (int m = 0; m < NS; ++m) { h[m][0] = 0.f; h[m][1] = 0.f; }

    if (mgrp == 0) {   // prefetch x for st=0
        const int tt0 = dir ? (T - 1) : 0;
#pragma unroll
        for (int m = 0; m < NS; ++m)
#pragma unroll
            for (int g = 0; g < 3; ++g)
#pragma unroll
                for (int t = 0; t < 2; ++t)
                    xv[m][g][t] = xgm[m][(long)tt0 * 1536 + g * 256 + d0 + 16 * t];
    }
    __syncthreads();

    for (int st = 0; st < T; ++st) {
        const int cur = st & 1, nxt = cur ^ 1;
        // deferred out store of h(st-1): drains under this step's MFMA
        if (st > 0 && mgrp == 0) {
            const int tp = dir ? (T - st) : (st - 1);
#pragma unroll
            for (int m = 0; m < NS; ++m) {
                outm[m][(long)tp * 512 + d0] = ostage[m][0];
                outm[m][(long)tp * 512 + d0 + 16] = ostage[m][1];
            }
        }
        // ---- P1: acc = h(st-1) @ Whh^T (wave's 6 gate-tiles) ----
        f32x4 acc[6];
        f32x4 zero = {0.f, 0.f, 0.f, 0.f};
#pragma unroll
        for (int gi = 0; gi < 6; ++gi) acc[gi] = zero;
#pragma unroll
        for (int kc = 0; kc < 8; ++kc) {
            bf16x8 a = __builtin_bit_cast(bf16x8,
                *(const ushort8*)(&hbf[cur][fm * HBS + kc * 32 + fq]));
#pragma unroll
            for (int gi = 0; gi < 6; ++gi)
                acc[gi] = __builtin_amdgcn_mfma_f32_16x16x32_bf16(a, wfrag[gi][kc], acc[gi], 0, 0, 0);
        }
        // ---- P2: in-wave gate nonlinearity + h update (lanes 0..15) ----
        if (mgrp == 0) {
#pragma unroll
            for (int m = 0; m < NS; ++m)
#pragma unroll
                for (int t = 0; t < 2; ++t) {
                    float xr = b2f(xv[m][0][t]);
                    float xz = b2f(xv[m][1][t]);
                    float xn = b2f(xv[m][2][t]);
                    float r = sigmoidf_(xr + acc[0 + t][m] + bhhv[0][t]);
                    float z = sigmoidf_(xz + acc[2 + t][m] + bhhv[1][t]);
                    float n = tanhf_(xn + r * (acc[4 + t][m] + bhhv[2][t]));
                    h[m][t] = (1.f - z) * n + z * h[m][t];
                    ushort_t hb = f2b(h[m][t]);
                    hbf[nxt][m * HBS + d0 + 16 * t] = hb;
                    ostage[m][t] = hb;
                }
            // prefetch x for st+1 (full P1 of latency cover)
            const int stn = (st + 1 < T) ? (st + 1) : st;
            const int ttn = dir ? (T - 1 - stn) : stn;
#pragma unroll
            for (int m = 0; m < NS; ++m)
#pragma unroll
                for (int g = 0; g < 3; ++g)
#pragma unroll
                    for (int t = 0; t < 2; ++t)
                        xv[m][g][t] = xgm[m][(long)ttn * 1536 + g * 256 + d0 + 16 * t];
        }
        __syncthreads();
    }
    if (mgrp == 0) {   // final deferred store
        const int tl = dir ? 0 : (T - 1);
#pragma unroll
        for (int m = 0; m < NS; ++m) {
            outm[m][(long)tl * 512 + d0] = ostage[m][0];
            outm[m][(long)tl * 512 + d0 + 16] = ostage[m][1];
        }
    }
}

// ---------------------------------------------------------------------------
// Word attention: per sentence, scores=tanh(out.attW+b), softmax over 64 words,
// weighted sum -> sent_vecs[s][512] (fp32). 256 blocks x 256 threads.
// ---------------------------------------------------------------------------
__global__ void attn_word(const ushort_t* __restrict__ wout,
                          const float* __restrict__ attW,
                          const float* __restrict__ attB,
                          float* __restrict__ svec)
{
    __shared__ float part[64][4];
    __shared__ float aw[64];
    const int s = blockIdx.x, tid = threadIdx.x;
    const int w = tid >> 2, q = tid & 3;
    const ushort_t* row = wout + ((long)(s * 64 + w)) * 512 + q * 128;
    const float* ap = attW + q * 128;
    float sum = 0.f;
    for (int i = 0; i < 128; i += 8) {
        ushort8 a = *(const ushort8*)(row + i);
        float4 b0 = *(const float4*)(ap + i);
        float4 b1 = *(const float4*)(ap + i + 4);
        sum += b2f(a[0]) * b0.x + b2f(a[1]) * b0.y + b2f(a[2]) * b0.z + b2f(a[3]) * b0.w
             + b2f(a[4]) * b1.x + b2f(a[5]) * b1.y + b2f(a[6]) * b1.z + b2f(a[7]) * b1.w;
    }
    part[w][q] = sum;
    __syncthreads();
    if (tid < 64) {
        float sc = tanhf_(part[tid][0] + part[tid][1] + part[tid][2] + part[tid][3] + attB[0]);
        float m = sc;
#pragma unroll
        for (int o = 32; o >= 1; o >>= 1) m = fmaxf(m, __shfl_xor(m, o, 64));
        float e = __expf(sc - m);
        float se = e;
#pragma unroll
        for (int o = 32; o >= 1; o >>= 1) se += __shfl_xor(se, o, 64);
        aw[tid] = e / se;
    }
    __syncthreads();
    const int d = tid * 2;
    float a0 = 0.f, a1 = 0.f;
    const ushort_t* col = wout + ((long)(s * 64)) * 512 + d;
#pragma unroll 4
    for (int w2 = 0; w2 < 64; ++w2) {
        u32 v = *(const u32*)(col + (long)w2 * 512);
        float wg = aw[w2];
        a0 += wg * b2f((ushort_t)v);
        a1 += wg * b2f((ushort_t)(v >> 16));
    }
    *(float2*)(svec + (long)s * 512 + d) = make_float2(a0, a1);
}

// ---------------------------------------------------------------------------
// Sentence attention over 256 steps -> doc vec (fp32). 1 block x 256 threads.
// ---------------------------------------------------------------------------
__global__ void attn_sent(const ushort_t* __restrict__ sout,
                          const float* __restrict__ attW,
                          const float* __restrict__ attB,
                          float* __restrict__ doc)
{
    __shared__ float aw[256];
    __shared__ float red[8];
    const int tid = threadIdx.x;
    const ushort_t* row = sout + (long)tid * 512;
    float sum = 0.f;
    for (int i = 0; i < 512; i += 8) {
        ushort8 a = *(const ushort8*)(row + i);
        float4 b0 = *(const float4*)(attW + i);
        float4 b1 = *(const float4*)(attW + i + 4);
        sum += b2f(a[0]) * b0.x + b2f(a[1]) * b0.y + b2f(a[2]) * b0.z + b2f(a[3]) * b0.w
             + b2f(a[4]) * b1.x + b2f(a[5]) * b1.y + b2f(a[6]) * b1.z + b2f(a[7]) * b1.w;
    }
    float sc = tanhf_(sum + attB[0]);
    float m = sc;
#pragma unroll
    for (int o = 32; o >= 1; o >>= 1) m = fmaxf(m, __shfl_xor(m, o, 64));
    if ((tid & 63) == 0) red[tid >> 6] = m;
    __syncthreads();
    m = fmaxf(fmaxf(red[0], red[1]), fmaxf(red[2], red[3]));
    float e = __expf(sc - m);
    float se = e;
#pragma unroll
    for (int o = 32; o >= 1; o >>= 1) se += __shfl_xor(se, o, 64);
    if ((tid & 63) == 0) red[4 + (tid >> 6)] = se;
    __syncthreads();
    se = red[4] + red[5] + red[6] + red[7];
    aw[tid] = e / se;
    __syncthreads();
    const int d = tid * 2;
    float a0 = 0.f, a1 = 0.f;
    for (int t2 = 0; t2 < 256; ++t2) {
        u32 v = *(const u32*)(sout + (long)t2 * 512 + d);
        float w = aw[t2];
        a0 += w * b2f((ushort_t)v);
        a1 += w * b2f((ushort_t)(v >> 16));
    }
    doc[d] = a0;
    doc[d + 1] = a1;
}

// ---------------------------------------------------------------------------
// Classifier + softmax -> d_out[10] fp32. 1 wave.
// ---------------------------------------------------------------------------
__global__ void classify(const float* __restrict__ doc, const float* __restrict__ clsW,
                         const float* __restrict__ clsB, float* __restrict__ outp)
{
    const int lane = threadIdx.x;
    float logit = -1e30f;
    if (lane < 10) {
        float s = clsB[lane];
        const float* wr = clsW + lane * 512;
        for (int i = 0; i < 512; ++i) s += doc[i] * wr[i];
        logit = s;
    }
    float m = logit;
#pragma unroll
    for (int o = 32; o >= 1; o >>= 1) m = fmaxf(m, __shfl_xor(m, o, 64));
    float e = (lane < 10) ? __expf(logit - m) : 0.f;
    float se = e;
#pragma unroll
    for (int o = 32; o >= 1; o >>= 1) se += __shfl_xor(se, o, 64);
    if (lane < 10) outp[lane] = e / se;
}

extern "C" void kernel_launch(void* const* d_in, const int* in_sizes, int n_in,
                              void* d_out, int out_size, void* d_ws, size_t ws_size,
                              hipStream_t stream)
{
    const int*   tokens = (const int*)d_in[0];
    const float* emb    = (const float*)d_in[1];
    const float* wWihF  = (const float*)d_in[2];
    const float* wWhhF  = (const float*)d_in[3];
    const float* wBihF  = (const float*)d_in[4];
    const float* wBhhF  = (const float*)d_in[5];
    const float* wWihB  = (const float*)d_in[6];
    const float* wWhhB  = (const float*)d_in[7];
    const float* wBihB  = (const float*)d_in[8];
    const float* wBhhB  = (const float*)d_in[9];
    const float* sWihF  = (const float*)d_in[10];
    const float* sWhhF  = (const float*)d_in[11];
    const float* sBihF  = (const float*)d_in[12];
    const float* sBhhF  = (const float*)d_in[13];
    const float* sWihB  = (const float*)d_in[14];
    const float* sWhhB  = (const float*)d_in[15];
    const float* sBihB  = (const float*)d_in[16];
    const float* sBhhB  = (const float*)d_in[17];
    const float* wAttW  = (const float*)d_in[18];
    const float* wAttB  = (const float*)d_in[19];
    const float* sAttW  = (const float*)d_in[20];
    const float* sAttB  = (const float*)d_in[21];
    const float* clsW   = (const float*)d_in[22];
    const float* clsB   = (const float*)d_in[23];

    char* ws = (char*)d_ws;
    ushort_t* xg   = (ushort_t*)(ws);              // [16384][1536] bf16  50,331,648 B
    ushort_t* wout = (ushort_t*)(ws + 50331648);   // [16384][512]  bf16  16,777,216 B
    float*    svec = (float*)(ws + 67108864);      // [256][512]    fp32     524,288 B
    ushort_t* sxg  = (ushort_t*)(ws + 67633152);   // [256][1536]   bf16     786,432 B
    ushort_t* sout = (ushort_t*)(ws + 68419584);   // [256][512]    bf16     262,144 B
    float*    doc  = (float*)(ws + 68681728);      // [512]         fp32       2,048 B

    // word level
    gemm_xg<<<dim3(12, 128), 256, 0, stream>>>(emb, tokens, wWihF, wWihB, wBihF, wBihB, xg, 256);
    gru_level<2><<<256, 512, 0, stream>>>(wWhhF, wWhhB, wBhhF, wBhhB, xg, wout, 64);
    attn_word<<<256, 256, 0, stream>>>(wout, wAttW, wAttB, svec);
    // sentence level
    gemm_xg<<<dim3(12, 2), 256, 0, stream>>>(svec, nullptr, sWihF, sWihB, sBihF, sBihB, sxg, 512);
    gru_level<1><<<2, 512, 0, stream>>>(sWhhF, sWhhB, sBhhF, sBhhB, sxg, sout, 256);
    attn_sent<<<1, 256, 0, stream>>>(sout, sAttW, sAttB, doc);
    classify<<<1, 64, 0, stream>>>(doc, clsW, clsB, (float*)d_out);
}

// Round 4
// 842.487 us; speedup vs baseline: 1.1288x; 1.1288x over previous
//
#include <hip/hip_runtime.h>
#include <stdint.h>

typedef unsigned short ushort_t;
typedef uint32_t u32;
typedef __bf16 bf16;
typedef bf16 bf16x8 __attribute__((ext_vector_type(8)));
typedef float f32x4 __attribute__((ext_vector_type(4)));
typedef ushort_t ushort8 __attribute__((ext_vector_type(8)));

__device__ __forceinline__ float b2f(ushort_t u) {
    u32 x = ((u32)u) << 16;
    return __builtin_bit_cast(float, x);
}
__device__ __forceinline__ ushort_t f2b(float f) {
    bf16 h = (bf16)f;
    return __builtin_bit_cast(ushort_t, h);
}
__device__ __forceinline__ float sigmoidf_(float x) { return 1.0f / (1.0f + __expf(-x)); }
__device__ __forceinline__ float tanhf_(float x) { return 1.0f - 2.0f / (1.0f + __expf(2.0f * x)); }

// load 8 consecutive fp32, round-to-nearest to bf16, return packed ushort8
__device__ __forceinline__ ushort8 cvt8(const float* __restrict__ p) {
    float4 v0 = *(const float4*)p;
    float4 v1 = *(const float4*)(p + 4);
    ushort8 r;
    r[0] = f2b(v0.x); r[1] = f2b(v0.y); r[2] = f2b(v0.z); r[3] = f2b(v0.w);
    r[4] = f2b(v1.x); r[5] = f2b(v1.y); r[6] = f2b(v1.z); r[7] = f2b(v1.w);
    return r;
}

// ---------------------------------------------------------------------------
// GEMM: C[M][1536] = A[M][K] @ [WF;WB]^T + [bF;bB]  (A,W,b fp32; C bf16).
// A row optionally gathered via tokens. 128x128 tile, 256 thr, bf16 MFMA.
// ---------------------------------------------------------------------------
#define TPAD 40  // LDS tile row stride (bf16): 32 data + 8 pad

__global__ __launch_bounds__(256) void gemm_xg(
    const float* __restrict__ A, const int* __restrict__ tok,
    const float* __restrict__ WF, const float* __restrict__ WB,
    const float* __restrict__ bF, const float* __restrict__ bB,
    ushort_t* __restrict__ C, int K)
{
    __shared__ ushort_t aT[128 * TPAD];
    __shared__ ushort_t bT[128 * TPAD];
    const int tid = threadIdx.x;
    const int lane = tid & 63, wv = tid >> 6;
    const int bn0 = blockIdx.x * 128;
    const int rm0 = blockIdx.y * 128;
    const int wm = (wv & 1) * 64, wn = (wv >> 1) * 64;

    f32x4 acc[4][4];
    f32x4 zero = {0.f, 0.f, 0.f, 0.f};
#pragma unroll
    for (int i = 0; i < 4; i++)
#pragma unroll
        for (int j = 0; j < 4; j++) acc[i][j] = zero;

    const int sr = tid >> 1;          // staged row 0..127
    const int sk = (tid & 1) * 16;    // k offset 0/16
    long arow = tok ? (long)tok[rm0 + sr] : (long)(rm0 + sr);
    const float* aSrc = A + arow * K + sk;
    int ng = bn0 + sr;
    const float* bSrc = (ng < 768 ? WF + (long)ng * K : WB + (long)(ng - 768) * K) + sk;

    const int nkc = K / 32;
    const int fm = lane & 15, fq = (lane >> 4) * 8;
    for (int kc = 0; kc < nkc; ++kc) {
        ushort8 av0 = cvt8(aSrc + kc * 32);
        ushort8 av1 = cvt8(aSrc + kc * 32 + 8);
        ushort8 bv0 = cvt8(bSrc + kc * 32);
        ushort8 bv1 = cvt8(bSrc + kc * 32 + 8);
        __syncthreads();
        *(ushort8*)(aT + sr * TPAD + sk) = av0;
        *(ushort8*)(aT + sr * TPAD + sk + 8) = av1;
        *(ushort8*)(bT + sr * TPAD + sk) = bv0;
        *(ushort8*)(bT + sr * TPAD + sk + 8) = bv1;
        __syncthreads();
        bf16x8 af[4], bfg[4];
#pragma unroll
        for (int i = 0; i < 4; i++)
            af[i] = __builtin_bit_cast(bf16x8, *(const ushort8*)(aT + (wm + i * 16 + fm) * TPAD + fq));
#pragma unroll
        for (int j = 0; j < 4; j++)
            bfg[j] = __builtin_bit_cast(bf16x8, *(const ushort8*)(bT + (wn + j * 16 + fm) * TPAD + fq));
#pragma unroll
        for (int i = 0; i < 4; i++)
#pragma unroll
            for (int j = 0; j < 4; j++)
                acc[i][j] = __builtin_amdgcn_mfma_f32_16x16x32_bf16(af[i], bfg[j], acc[i][j], 0, 0, 0);
    }
    const int fr0 = (lane >> 4) * 4;
#pragma unroll
    for (int j = 0; j < 4; j++) {
        int col = bn0 + wn + j * 16 + fm;
        float bias = (col < 768) ? bF[col] : bB[col - 768];
#pragma unroll
        for (int i = 0; i < 4; i++) {
#pragma unroll
            for (int r = 0; r < 4; r++) {
                int row = rm0 + wm + i * 16 + fr0 + r;
                C[(long)row * 1536 + col] = f2b(acc[i][j][r] + bias);
            }
        }
    }
}

// ---------------------------------------------------------------------------
// Register-persistent bi-GRU, v3: no global memory ops in the steady-state
// step loop. x gates and h outputs are staged through double-buffered LDS
// chunk buffers (16 rows = CS steps x NS sentences), loaded/flushed
// cooperatively (coalesced) once per chunk, so per-step __syncthreads has no
// outstanding vmem to drain (the s_waitcnt vmcnt(0) barrier-drain pathology).
// 512 threads = 8 waves. Wave w owns h-dims [32w,32w+32) and holds the r/z/n
// gate rows for those dims as 6 16-row MFMA B-tiles (192 regs, VGPR+AGPR).
// C layout row=(lane>>4)*4+reg, col=lane&15 -> lanes 0..15 hold sentences.
// grid = 2 * (nSent/NS); blockIdx&1 = direction. PyTorch gate order r,z,n.
// ---------------------------------------------------------------------------
#define HBS 264   // hbf row stride (bf16): 256 + 8 pad
#define XRS 776   // x-chunk row stride (bf16): 768 + 8 pad
#define ORS 264   // out-chunk row stride (bf16): 256 + 8 pad

template<int NS, int CS>   // NS*CS == 16
__global__ __launch_bounds__(512, 2) void gru_level(
    const float* __restrict__ WhhF, const float* __restrict__ WhhB,
    const float* __restrict__ bhhF, const float* __restrict__ bhhB,
    const ushort_t* __restrict__ xg,   // [nSent*T][1536] bf16 (F cols 0..767, B 768..1535)
    ushort_t* __restrict__ out,        // [nSent*T][512] bf16 (F dims 0..255, B 256..511)
    int T)
{
    __shared__ ushort_t hbf[2][16 * HBS];
    __shared__ ushort_t xch[2][16 * XRS];
    __shared__ ushort_t och[2][16 * ORS];

    const int tid = threadIdx.x, lane = tid & 63, wv = tid >> 6;
    const int dir = blockIdx.x & 1;
    const int grp = blockIdx.x >> 1;
    const float* Whh = dir ? WhhB : WhhF;
    const float* bhh = dir ? bhhB : bhhF;
    const int dirOff = dir * 768;

    const int fm = lane & 15, fq = (lane >> 4) * 8;
    const int mgrp = lane >> 4;
    const int d0 = 32 * wv + fm;       // t=0 dim owned by this lane; t=1 is +16

    // persistent weights: tile (g,t) covers gate-rows g*256 + 32w + 16t .. +16
    bf16x8 wfrag[6][8];
#pragma unroll
    for (int g = 0; g < 3; ++g)
#pragma unroll
        for (int t = 0; t < 2; ++t) {
            const float* wrow = Whh + (long)(g * 256 + 32 * wv + 16 * t + fm) * 256 + fq;
#pragma unroll
            for (int kc = 0; kc < 8; ++kc)
                wfrag[g * 2 + t][kc] = __builtin_bit_cast(bf16x8, cvt8(wrow + kc * 32));
        }

    float bhhv[3][2];
#pragma unroll
    for (int g = 0; g < 3; ++g)
#pragma unroll
        for (int t = 0; t < 2; ++t)
            bhhv[g][t] = bhh[g * 256 + d0 + 16 * t];

    // zero both h buffers (rows >= NS stay zero forever)
    for (int i = tid; i < 16 * HBS; i += 512) { hbf[0][i] = 0; hbf[1][i] = 0; }

    // per-sentence base pointers (NS <= 2)
    const int s0 = grp * NS;
    const ushort_t* xgm0 = xg + (long)s0 * T * 1536 + dirOff;
    const ushort_t* xgm1 = xg + (long)(s0 + (NS > 1 ? 1 : 0)) * T * 1536 + dirOff;
    ushort_t* outm0 = out + (long)s0 * T * 512 + dir * 256;
    ushort_t* outm1 = out + (long)(s0 + (NS > 1 ? 1 : 0)) * T * 512 + dir * 256;

    float h[NS][2];
#pragma unroll
    for (int m = 0; m < NS; ++m) { h[m][0] = 0.f; h[m][1] = 0.f; }

    const int nch = T / CS;

    // ---- stage x chunk c2 into xch[c2&1] (cooperative, coalesced) ----
    auto stage_x = [&](int c2) {
        ushort8 val[3];
        int row[3], c8[3];
#pragma unroll
        for (int i = 0; i < 3; ++i) {
            int v = tid + i * 512;                 // 1536 vectors of 8
            row[i] = v / 96; c8[i] = v - row[i] * 96;
            int sc = row[i] / NS, m = row[i] - sc * NS;
            int stg = c2 * CS + sc;
            int tt = dir ? (T - 1 - stg) : stg;
            const ushort_t* xp = (NS == 1 || m == 0) ? xgm0 : xgm1;
            val[i] = *(const ushort8*)(xp + (long)tt * 1536 + c8[i] * 8);
        }
#pragma unroll
        for (int i = 0; i < 3; ++i)
            *(ushort8*)(&xch[c2 & 1][row[i] * XRS + c8[i] * 8]) = val[i];
    };

    // ---- flush out chunk c2 from och[c2&1] (cooperative, coalesced) ----
    auto flush_o = [&](int c2) {
        int v = tid;                               // 512 vectors of 8
        int row = v >> 5, c8 = v & 31;
        int sc = row / NS, m = row - sc * NS;
        int stg = c2 * CS + sc;
        int tt = dir ? (T - 1 - stg) : stg;
        ushort8 val = *(const ushort8*)(&och[c2 & 1][row * ORS + c8 * 8]);
        ushort_t* op = (NS == 1 || m == 0) ? outm0 : outm1;
        *(ushort8*)(op + (long)tt * 512 + c8 * 8) = val;
    };

    stage_x(0);
    __syncthreads();

    for (int c = 0; c < nch; ++c) {
        const int buf = c & 1;
        if (c > 0) flush_o(c - 1);
        if (c + 1 < nch) stage_x(c + 1);
        for (int sc = 0; sc < CS; ++sc) {
            const int st = c * CS + sc;
            const int cur = st & 1, nxt = cur ^ 1;
            // ---- P1: acc = h(st-1) @ Whh^T (wave's 6 gate-tiles) ----
            f32x4 acc[6];
            f32x4 zero = {0.f, 0.f, 0.f, 0.f};
#pragma unroll
            for (int gi = 0; gi < 6; ++gi) acc[gi] = zero;
#pragma unroll
            for (int kc = 0; kc < 8; ++kc) {
                bf16x8 a = __builtin_bit_cast(bf16x8,
                    *(const ushort8*)(&hbf[cur][fm * HBS + kc * 32 + fq]));
#pragma unroll
                for (int gi = 0; gi < 6; ++gi)
                    acc[gi] = __builtin_amdgcn_mfma_f32_16x16x32_bf16(a, wfrag[gi][kc], acc[gi], 0, 0, 0);
            }
            // ---- P2: in-wave gate nonlinearity + h update (lanes 0..15) ----
            if (mgrp == 0) {
#pragma unroll
                for (int m = 0; m < NS; ++m) {
                    const int xrow = (sc * NS + m) * XRS;
#pragma unroll
                    for (int t = 0; t < 2; ++t) {
                        float xr = b2f(xch[buf][xrow + d0 + 16 * t]);
                        float xz = b2f(xch[buf][xrow + 256 + d0 + 16 * t]);
                        float xn = b2f(xch[buf][xrow + 512 + d0 + 16 * t]);
                        float r = sigmoidf_(xr + acc[0 + t][m] + bhhv[0][t]);
                        float z = sigmoidf_(xz + acc[2 + t][m] + bhhv[1][t]);
                        float n = tanhf_(xn + r * (acc[4 + t][m] + bhhv[2][t]));
                        h[m][t] = (1.f - z) * n + z * h[m][t];
                        ushort_t hb = f2b(h[m][t]);
                        hbf[nxt][m * HBS + d0 + 16 * t] = hb;
                        och[buf][(sc * NS + m) * ORS + d0 + 16 * t] = hb;
                    }
                }
            }
            __syncthreads();
        }
    }
    flush_o(nch - 1);
}

// ---------------------------------------------------------------------------
// Word attention: per sentence, scores=tanh(out.attW+b), softmax over 64 words,
// weighted sum -> sent_vecs[s][512] (fp32). 256 blocks x 256 threads.
// ---------------------------------------------------------------------------
__global__ void attn_word(const ushort_t* __restrict__ wout,
                          const float* __restrict__ attW,
                          const float* __restrict__ attB,
                          float* __restrict__ svec)
{
    __shared__ float part[64][4];
    __shared__ float aw[64];
    const int s = blockIdx.x, tid = threadIdx.x;
    const int w = tid >> 2, q = tid & 3;
    const ushort_t* row = wout + ((long)(s * 64 + w)) * 512 + q * 128;
    const float* ap = attW + q * 128;
    float sum = 0.f;
    for (int i = 0; i < 128; i += 8) {
        ushort8 a = *(const ushort8*)(row + i);
        float4 b0 = *(const float4*)(ap + i);
        float4 b1 = *(const float4*)(ap + i + 4);
        sum += b2f(a[0]) * b0.x + b2f(a[1]) * b0.y + b2f(a[2]) * b0.z + b2f(a[3]) * b0.w
             + b2f(a[4]) * b1.x + b2f(a[5]) * b1.y + b2f(a[6]) * b1.z + b2f(a[7]) * b1.w;
    }
    part[w][q] = sum;
    __syncthreads();
    if (tid < 64) {
        float sc = tanhf_(part[tid][0] + part[tid][1] + part[tid][2] + part[tid][3] + attB[0]);
        float m = sc;
#pragma unroll
        for (int o = 32; o >= 1; o >>= 1) m = fmaxf(m, __shfl_xor(m, o, 64));
        float e = __expf(sc - m);
        float se = e;
#pragma unroll
        for (int o = 32; o >= 1; o >>= 1) se += __shfl_xor(se, o, 64);
        aw[tid] = e / se;
    }
    __syncthreads();
    const int d = tid * 2;
    float a0 = 0.f, a1 = 0.f;
    const ushort_t* col = wout + ((long)(s * 64)) * 512 + d;
#pragma unroll 4
    for (int w2 = 0; w2 < 64; ++w2) {
        u32 v = *(const u32*)(col + (long)w2 * 512);
        float wg = aw[w2];
        a0 += wg * b2f((ushort_t)v);
        a1 += wg * b2f((ushort_t)(v >> 16));
    }
    *(float2*)(svec + (long)s * 512 + d) = make_float2(a0, a1);
}

// ---------------------------------------------------------------------------
// Sentence attention over 256 steps -> doc vec (fp32). 1 block x 256 threads.
// ---------------------------------------------------------------------------
__global__ void attn_sent(const ushort_t* __restrict__ sout,
                          const float* __restrict__ attW,
                          const float* __restrict__ attB,
                          float* __restrict__ doc)
{
    __shared__ float aw[256];
    __shared__ float red[8];
    const int tid = threadIdx.x;
    const ushort_t* row = sout + (long)tid * 512;
    float sum = 0.f;
    for (int i = 0; i < 512; i += 8) {
        ushort8 a = *(const ushort8*)(row + i);
        float4 b0 = *(const float4*)(attW + i);
        float4 b1 = *(const float4*)(attW + i + 4);
        sum += b2f(a[0]) * b0.x + b2f(a[1]) * b0.y + b2f(a[2]) * b0.z + b2f(a[3]) * b0.w
             + b2f(a[4]) * b1.x + b2f(a[5]) * b1.y + b2f(a[6]) * b1.z + b2f(a[7]) * b1.w;
    }
    float sc = tanhf_(sum + attB[0]);
    float m = sc;
#pragma unroll
    for (int o = 32; o >= 1; o >>= 1) m = fmaxf(m, __shfl_xor(m, o, 64));
    if ((tid & 63) == 0) red[tid >> 6] = m;
    __syncthreads();
    m = fmaxf(fmaxf(red[0], red[1]), fmaxf(red[2], red[3]));
    float e = __expf(sc - m);
    float se = e;
#pragma unroll
    for (int o = 32; o >= 1; o >>= 1) se += __shfl_xor(se, o, 64);
    if ((tid & 63) == 0) red[4 + (tid >> 6)] = se;
    __syncthreads();
    se = red[4] + red[5] + red[6] + red[7];
    aw[tid] = e / se;
    __syncthreads();
    const int d = tid * 2;
    float a0 = 0.f, a1 = 0.f;
    for (int t2 = 0; t2 < 256; ++t2) {
        u32 v = *(const u32*)(sout + (long)t2 * 512 + d);
        float w = aw[t2];
        a0 += w * b2f((ushort_t)v);
        a1 += w * b2f((ushort_t)(v >> 16));
    }
    doc[d] = a0;
    doc[d + 1] = a1;
}

// ---------------------------------------------------------------------------
// Classifier + softmax -> d_out[10] fp32. 1 wave.
// ---------------------------------------------------------------------------
__global__ void classify(const float* __restrict__ doc, const float* __restrict__ clsW,
                         const float* __restrict__ clsB, float* __restrict__ outp)
{
    const int lane = threadIdx.x;
    float logit = -1e30f;
    if (lane < 10) {
        float s = clsB[lane];
        const float* wr = clsW + lane * 512;
        for (int i = 0; i < 512; ++i) s += doc[i] * wr[i];
        logit = s;
    }
    float m = logit;
#pragma unroll
    for (int o = 32; o >= 1; o >>= 1) m = fmaxf(m, __shfl_xor(m, o, 64));
    float e = (lane < 10) ? __expf(logit - m) : 0.f;
    float se = e;
#pragma unroll
    for (int o = 32; o >= 1; o >>= 1) se += __shfl_xor(se, o, 64);
    if (lane < 10) outp[lane] = e / se;
}

extern "C" void kernel_launch(void* const* d_in, const int* in_sizes, int n_in,
                              void* d_out, int out_size, void* d_ws, size_t ws_size,
                              hipStream_t stream)
{
    const int*   tokens = (const int*)d_in[0];
    const float* emb    = (const float*)d_in[1];
    const float* wWihF  = (const float*)d_in[2];
    const float* wWhhF  = (const float*)d_in[3];
    const float* wBihF  = (const float*)d_in[4];
    const float* wBhhF  = (const float*)d_in[5];
    const float* wWihB  = (const float*)d_in[6];
    const float* wWhhB  = (const float*)d_in[7];
    const float* wBihB  = (const float*)d_in[8];
    const float* wBhhB  = (const float*)d_in[9];
    const float* sWihF  = (const float*)d_in[10];
    const float* sWhhF  = (const float*)d_in[11];
    const float* sBihF  = (const float*)d_in[12];
    const float* sBhhF  = (const float*)d_in[13];
    const float* sWihB  = (const float*)d_in[14];
    const float* sWhhB  = (const float*)d_in[15];
    const float* sBihB  = (const float*)d_in[16];
    const float* sBhhB  = (const float*)d_in[17];
    const float* wAttW  = (const float*)d_in[18];
    const float* wAttB  = (const float*)d_in[19];
    const float* sAttW  = (const float*)d_in[20];
    const float* sAttB  = (const float*)d_in[21];
    const float* clsW   = (const float*)d_in[22];
    const float* clsB   = (const float*)d_in[23];

    char* ws = (char*)d_ws;
    ushort_t* xg   = (ushort_t*)(ws);              // [16384][1536] bf16  50,331,648 B
    ushort_t* wout = (ushort_t*)(ws + 50331648);   // [16384][512]  bf16  16,777,216 B
    float*    svec = (float*)(ws + 67108864);      // [256][512]    fp32     524,288 B
    ushort_t* sxg  = (ushort_t*)(ws + 67633152);   // [256][1536]   bf16     786,432 B
    ushort_t* sout = (ushort_t*)(ws + 68419584);   // [256][512]    bf16     262,144 B
    float*    doc  = (float*)(ws + 68681728);      // [512]         fp32       2,048 B

    // word level
    gemm_xg<<<dim3(12, 128), 256, 0, stream>>>(emb, tokens, wWihF, wWihB, wBihF, wBihB, xg, 256);
    gru_level<2, 8><<<256, 512, 0, stream>>>(wWhhF, wWhhB, wBhhF, wBhhB, xg, wout, 64);
    attn_word<<<256, 256, 0, stream>>>(wout, wAttW, wAttB, svec);
    // sentence level
    gemm_xg<<<dim3(12, 2), 256, 0, stream>>>(svec, nullptr, sWihF, sWihB, sBihF, sBihB, sxg, 512);
    gru_level<1, 16><<<2, 512, 0, stream>>>(sWhhF, sWhhB, sBhhF, sBhhB, sxg, sout, 256);
    attn_sent<<<1, 256, 0, stream>>>(sout, sAttW, sAttB, doc);
    classify<<<1, 64, 0, stream>>>(doc, clsW, clsB, (float*)d_out);
}

// Round 5
// 823.634 us; speedup vs baseline: 1.1546x; 1.0229x over previous
//
#include <hip/hip_runtime.h>
#include <stdint.h>

typedef unsigned short ushort_t;
typedef uint32_t u32;
typedef __bf16 bf16;
typedef bf16 bf16x8 __attribute__((ext_vector_type(8)));
typedef float f32x4 __attribute__((ext_vector_type(4)));
typedef ushort_t ushort8 __attribute__((ext_vector_type(8)));

__device__ __forceinline__ float b2f(ushort_t u) {
    u32 x = ((u32)u) << 16;
    return __builtin_bit_cast(float, x);
}
__device__ __forceinline__ ushort_t f2b(float f) {
    bf16 h = (bf16)f;
    return __builtin_bit_cast(ushort_t, h);
}
__device__ __forceinline__ float sigmoidf_(float x) { return 1.0f / (1.0f + __expf(-x)); }
__device__ __forceinline__ float tanhf_(float x) { return 1.0f - 2.0f / (1.0f + __expf(2.0f * x)); }

// load 8 consecutive fp32, round-to-nearest to bf16, return packed ushort8
__device__ __forceinline__ ushort8 cvt8(const float* __restrict__ p) {
    float4 v0 = *(const float4*)p;
    float4 v1 = *(const float4*)(p + 4);
    ushort8 r;
    r[0] = f2b(v0.x); r[1] = f2b(v0.y); r[2] = f2b(v0.z); r[3] = f2b(v0.w);
    r[4] = f2b(v1.x); r[5] = f2b(v1.y); r[6] = f2b(v1.z); r[7] = f2b(v1.w);
    return r;
}

// ---------------------------------------------------------------------------
// GEMM: C[M][1536] = A[M][K] @ [WF;WB]^T + [bF;bB]  (A,W,b fp32; C bf16).
// A row optionally gathered via tokens. 128x128 tile, 256 thr, bf16 MFMA.
// ---------------------------------------------------------------------------
#define TPAD 40  // LDS tile row stride (bf16): 32 data + 8 pad

__global__ __launch_bounds__(256) void gemm_xg(
    const float* __restrict__ A, const int* __restrict__ tok,
    const float* __restrict__ WF, const float* __restrict__ WB,
    const float* __restrict__ bF, const float* __restrict__ bB,
    ushort_t* __restrict__ C, int K)
{
    __shared__ ushort_t aT[128 * TPAD];
    __shared__ ushort_t bT[128 * TPAD];
    const int tid = threadIdx.x;
    const int lane = tid & 63, wv = tid >> 6;
    const int bn0 = blockIdx.x * 128;
    const int rm0 = blockIdx.y * 128;
    const int wm = (wv & 1) * 64, wn = (wv >> 1) * 64;

    f32x4 acc[4][4];
    f32x4 zero = {0.f, 0.f, 0.f, 0.f};
#pragma unroll
    for (int i = 0; i < 4; i++)
#pragma unroll
        for (int j = 0; j < 4; j++) acc[i][j] = zero;

    const int sr = tid >> 1;          // staged row 0..127
    const int sk = (tid & 1) * 16;    // k offset 0/16
    long arow = tok ? (long)tok[rm0 + sr] : (long)(rm0 + sr);
    const float* aSrc = A + arow * K + sk;
    int ng = bn0 + sr;
    const float* bSrc = (ng < 768 ? WF + (long)ng * K : WB + (long)(ng - 768) * K) + sk;

    const int nkc = K / 32;
    const int fm = lane & 15, fq = (lane >> 4) * 8;
    for (int kc = 0; kc < nkc; ++kc) {
        ushort8 av0 = cvt8(aSrc + kc * 32);
        ushort8 av1 = cvt8(aSrc + kc * 32 + 8);
        ushort8 bv0 = cvt8(bSrc + kc * 32);
        ushort8 bv1 = cvt8(bSrc + kc * 32 + 8);
        __syncthreads();
        *(ushort8*)(aT + sr * TPAD + sk) = av0;
        *(ushort8*)(aT + sr * TPAD + sk + 8) = av1;
        *(ushort8*)(bT + sr * TPAD + sk) = bv0;
        *(ushort8*)(bT + sr * TPAD + sk + 8) = bv1;
        __syncthreads();
        bf16x8 af[4], bfg[4];
#pragma unroll
        for (int i = 0; i < 4; i++)
            af[i] = __builtin_bit_cast(bf16x8, *(const ushort8*)(aT + (wm + i * 16 + fm) * TPAD + fq));
#pragma unroll
        for (int j = 0; j < 4; j++)
            bfg[j] = __builtin_bit_cast(bf16x8, *(const ushort8*)(bT + (wn + j * 16 + fm) * TPAD + fq));
#pragma unroll
        for (int i = 0; i < 4; i++)
#pragma unroll
            for (int j = 0; j < 4; j++)
                acc[i][j] = __builtin_amdgcn_mfma_f32_16x16x32_bf16(af[i], bfg[j], acc[i][j], 0, 0, 0);
    }
    const int fr0 = (lane >> 4) * 4;
#pragma unroll
    for (int j = 0; j < 4; j++) {
        int col = bn0 + wn + j * 16 + fm;
        float bias = (col < 768) ? bF[col] : bB[col - 768];
#pragma unroll
        for (int i = 0; i < 4; i++) {
#pragma unroll
            for (int r = 0; r < 4; r++) {
                int row = rm0 + wm + i * 16 + fr0 + r;
                C[(long)row * 1536 + col] = f2b(acc[i][j][r] + bias);
            }
        }
    }
}

// ---------------------------------------------------------------------------
// Register-persistent bi-GRU, v4: conflict-free pre-swizzled A-fragment LDS.
// h is stored in LDS directly in MFMA A-fragment order: afrag[kc][lane] is the
// 16B fragment (A[m=lane&15][k=kc*32+(lane>>4)*8+j]); reads are ds_read_b128
// at kc*1024+lane*16 -> linear banks, zero conflicts (was 8-way conflicted:
// SQ_LDS_BANK_CONFLICT 131072 = 512 extra cyc/step). Rows m>=NS zeroed once.
// Update lanes scatter-write their dims (wave w's 32 dims land in kc==w).
// A-frag loads software-pipelined depth-3 (12 regs, avoids pressure-serialized
// kc loop at the 256-reg/wave budget). x-gate scalars prefetched by the 16
// active lanes BEFORE the MFMA block (latency covered by the MFMA loop).
// x/out staged through double-buffered LDS chunks (16 rows = CS steps x NS
// sentences), cooperative coalesced global I/O once per chunk.
// 512 thr = 8 waves; wave w owns h-dims [32w,32w+32), holds r/z/n gate rows
// as 6 16-col MFMA B-tiles (192 regs, VGPR+AGPR). C layout: n=lane&15,
// m=(lane>>4)*4+reg -> lanes 0..15 (mgrp==0) read acc[gi][m] directly.
// grid = 2 * (nSent/NS); blockIdx&1 = direction. PyTorch gate order r,z,n.
// ---------------------------------------------------------------------------
#define XRS 776   // x-chunk row stride (bf16): 768 + 8 pad
#define ORS 264   // out-chunk row stride (bf16): 256 + 8 pad

template<int NS, int CS>   // NS*CS == 16
__global__ __launch_bounds__(512, 2) void gru_level(
    const float* __restrict__ WhhF, const float* __restrict__ WhhB,
    const float* __restrict__ bhhF, const float* __restrict__ bhhB,
    const ushort_t* __restrict__ xg,   // [nSent*T][1536] bf16 (F cols 0..767, B 768..1535)
    ushort_t* __restrict__ out,        // [nSent*T][512] bf16 (F dims 0..255, B 256..511)
    int T)
{
    __shared__ ushort_t afrag[2][8 * 512];   // [buf][kc*512 + lane*8 + j]
    __shared__ ushort_t xch[2][16 * XRS];
    __shared__ ushort_t och[2][16 * ORS];

    const int tid = threadIdx.x, lane = tid & 63, wv = tid >> 6;
    const int dir = blockIdx.x & 1;
    const int grp = blockIdx.x >> 1;
    const float* Whh = dir ? WhhB : WhhF;
    const float* bhh = dir ? bhhB : bhhF;
    const int dirOff = dir * 768;

    const int fm = lane & 15;
    const int mgrp = lane >> 4;
    const int d0 = 32 * wv + fm;       // t=0 dim owned by this lane; t=1 is +16

    // persistent weights: tile (g,t) covers gate-rows g*256 + 32w + 16t .. +16
    bf16x8 wfrag[6][8];
#pragma unroll
    for (int g = 0; g < 3; ++g)
#pragma unroll
        for (int t = 0; t < 2; ++t) {
            const float* wrow = Whh + (long)(g * 256 + 32 * wv + 16 * t + fm) * 256 + mgrp * 8;
#pragma unroll
            for (int kc = 0; kc < 8; ++kc)
                wfrag[g * 2 + t][kc] = __builtin_bit_cast(bf16x8, cvt8(wrow + kc * 32));
        }

    float bhhv[3][2];
#pragma unroll
    for (int g = 0; g < 3; ++g)
#pragma unroll
        for (int t = 0; t < 2; ++t)
            bhhv[g][t] = bhh[g * 256 + d0 + 16 * t];

    // zero both afrag buffers (entries for m>=NS stay zero forever)
    for (int i = tid; i < 8 * 512; i += 512) { afrag[0][i] = 0; afrag[1][i] = 0; }

    // per-sentence base pointers (NS <= 2)
    const int s0 = grp * NS;
    const ushort_t* xgm0 = xg + (long)s0 * T * 1536 + dirOff;
    const ushort_t* xgm1 = xg + (long)(s0 + (NS > 1 ? 1 : 0)) * T * 1536 + dirOff;
    ushort_t* outm0 = out + (long)s0 * T * 512 + dir * 256;
    ushort_t* outm1 = out + (long)(s0 + (NS > 1 ? 1 : 0)) * T * 512 + dir * 256;

    float h[NS][2];
#pragma unroll
    for (int m = 0; m < NS; ++m) { h[m][0] = 0.f; h[m][1] = 0.f; }

    const int nch = T / CS;

    // ---- stage x chunk c2 into xch[c2&1] (cooperative, coalesced) ----
    auto stage_x = [&](int c2) {
        ushort8 val[3];
        int row[3], c8[3];
#pragma unroll
        for (int i = 0; i < 3; ++i) {
            int v = tid + i * 512;                 // 1536 vectors of 8
            row[i] = v / 96; c8[i] = v - row[i] * 96;
            int sc = row[i] / NS, m = row[i] - sc * NS;
            int stg = c2 * CS + sc;
            int tt = dir ? (T - 1 - stg) : stg;
            const ushort_t* xp = (NS == 1 || m == 0) ? xgm0 : xgm1;
            val[i] = *(const ushort8*)(xp + (long)tt * 1536 + c8[i] * 8);
        }
#pragma unroll
        for (int i = 0; i < 3; ++i)
            *(ushort8*)(&xch[c2 & 1][row[i] * XRS + c8[i] * 8]) = val[i];
    };

    // ---- flush out chunk c2 from och[c2&1] (cooperative, coalesced) ----
    auto flush_o = [&](int c2) {
        int v = tid;                               // 512 vectors of 8
        int row = v >> 5, c8 = v & 31;
        int sc = row / NS, m = row - sc * NS;
        int stg = c2 * CS + sc;
        int tt = dir ? (T - 1 - stg) : stg;
        ushort8 val = *(const ushort8*)(&och[c2 & 1][row * ORS + c8 * 8]);
        ushort_t* op = (NS == 1 || m == 0) ? outm0 : outm1;
        *(ushort8*)(op + (long)tt * 512 + c8 * 8) = val;
    };

    stage_x(0);
    __syncthreads();

#define LDA(BUF, KC) __builtin_bit_cast(bf16x8, *(const ushort8*)(&afrag[BUF][(KC) * 512 + lane * 8]))
#define MF6(AV, KC) { _Pragma("unroll") for (int gi = 0; gi < 6; ++gi) \
    acc[gi] = __builtin_amdgcn_mfma_f32_16x16x32_bf16(AV, wfrag[gi][KC], acc[gi], 0, 0, 0); }

    for (int c = 0; c < nch; ++c) {
        const int buf = c & 1;
        if (c > 0) flush_o(c - 1);
        if (c + 1 < nch) stage_x(c + 1);
        for (int sc = 0; sc < CS; ++sc) {
            const int st = c * CS + sc;
            const int cur = st & 1, nxt = cur ^ 1;
            // prefetch this step's x-gate scalars (16 active lanes, cheap)
            ushort_t xv[NS][3][2];
            if (mgrp == 0) {
#pragma unroll
                for (int m = 0; m < NS; ++m) {
                    const int xrow = (sc * NS + m) * XRS;
#pragma unroll
                    for (int g = 0; g < 3; ++g)
#pragma unroll
                        for (int t = 0; t < 2; ++t)
                            xv[m][g][t] = xch[buf][xrow + g * 256 + d0 + 16 * t];
                }
            }
            // ---- P1: acc = h(st-1) @ Whh^T, depth-3 pipelined A loads ----
            f32x4 acc[6];
            f32x4 zero = {0.f, 0.f, 0.f, 0.f};
#pragma unroll
            for (int gi = 0; gi < 6; ++gi) acc[gi] = zero;
            {
                bf16x8 t0 = LDA(cur, 0), t1 = LDA(cur, 1), t2 = LDA(cur, 2);
                MF6(t0, 0); t0 = LDA(cur, 3);
                MF6(t1, 1); t1 = LDA(cur, 4);
                MF6(t2, 2); t2 = LDA(cur, 5);
                MF6(t0, 3); t0 = LDA(cur, 6);
                MF6(t1, 4); t1 = LDA(cur, 7);
                MF6(t2, 5);
                MF6(t0, 6);
                MF6(t1, 7);
            }
            // ---- P2: in-wave gate nonlinearity + h update (lanes 0..15) ----
            if (mgrp == 0) {
#pragma unroll
                for (int m = 0; m < NS; ++m) {
#pragma unroll
                    for (int t = 0; t < 2; ++t) {
                        float xr = b2f(xv[m][0][t]);
                        float xz = b2f(xv[m][1][t]);
                        float xn = b2f(xv[m][2][t]);
                        float r = sigmoidf_(xr + acc[0 + t][m] + bhhv[0][t]);
                        float z = sigmoidf_(xz + acc[2 + t][m] + bhhv[1][t]);
                        float n = tanhf_(xn + r * (acc[4 + t][m] + bhhv[2][t]));
                        h[m][t] = (1.f - z) * n + z * h[m][t];
                        ushort_t hb = f2b(h[m][t]);
                        // afrag[nxt] write: dim d = 32*wv + 16t + fm lands at
                        // kc = wv, entry lane = (2t + (fm>>3))*16 + m, byte j = fm&7
                        afrag[nxt][wv * 512 + ((2 * t + (fm >> 3)) * 16 + m) * 8 + (fm & 7)] = hb;
                        och[buf][(sc * NS + m) * ORS + d0 + 16 * t] = hb;
                    }
                }
            }
            __syncthreads();
        }
    }
    flush_o(nch - 1);
#undef LDA
#undef MF6
}

// ---------------------------------------------------------------------------
// Word attention: per sentence, scores=tanh(out.attW+b), softmax over 64 words,
// weighted sum -> sent_vecs[s][512] (fp32). 256 blocks x 256 threads.
// ---------------------------------------------------------------------------
__global__ void attn_word(const ushort_t* __restrict__ wout,
                          const float* __restrict__ attW,
                          const float* __restrict__ attB,
                          float* __restrict__ svec)
{
    __shared__ float part[64][4];
    __shared__ float aw[64];
    const int s = blockIdx.x, tid = threadIdx.x;
    const int w = tid >> 2, q = tid & 3;
    const ushort_t* row = wout + ((long)(s * 64 + w)) * 512 + q * 128;
    const float* ap = attW + q * 128;
    float sum = 0.f;
    for (int i = 0; i < 128; i += 8) {
        ushort8 a = *(const ushort8*)(row + i);
        float4 b0 = *(const float4*)(ap + i);
        float4 b1 = *(const float4*)(ap + i + 4);
        sum += b2f(a[0]) * b0.x + b2f(a[1]) * b0.y + b2f(a[2]) * b0.z + b2f(a[3]) * b0.w
             + b2f(a[4]) * b1.x + b2f(a[5]) * b1.y + b2f(a[6]) * b1.z + b2f(a[7]) * b1.w;
    }
    part[w][q] = sum;
    __syncthreads();
    if (tid < 64) {
        float sc = tanhf_(part[tid][0] + part[tid][1] + part[tid][2] + part[tid][3] + attB[0]);
        float m = sc;
#pragma unroll
        for (int o = 32; o >= 1; o >>= 1) m = fmaxf(m, __shfl_xor(m, o, 64));
        float e = __expf(sc - m);
        float se = e;
#pragma unroll
        for (int o = 32; o >= 1; o >>= 1) se += __shfl_xor(se, o, 64);
        aw[tid] = e / se;
    }
    __syncthreads();
    const int d = tid * 2;
    float a0 = 0.f, a1 = 0.f;
    const ushort_t* col = wout + ((long)(s * 64)) * 512 + d;
#pragma unroll 4
    for (int w2 = 0; w2 < 64; ++w2) {
        u32 v = *(const u32*)(col + (long)w2 * 512);
        float wg = aw[w2];
        a0 += wg * b2f((ushort_t)v);
        a1 += wg * b2f((ushort_t)(v >> 16));
    }
    *(float2*)(svec + (long)s * 512 + d) = make_float2(a0, a1);
}

// ---------------------------------------------------------------------------
// Sentence attention over 256 steps -> doc vec (fp32). 1 block x 256 threads.
// ---------------------------------------------------------------------------
__global__ void attn_sent(const ushort_t* __restrict__ sout,
                          const float* __restrict__ attW,
                          const float* __restrict__ attB,
                          float* __restrict__ doc)
{
    __shared__ float aw[256];
    __shared__ float red[8];
    const int tid = threadIdx.x;
    const ushort_t* row = sout + (long)tid * 512;
    float sum = 0.f;
    for (int i = 0; i < 512; i += 8) {
        ushort8 a = *(const ushort8*)(row + i);
        float4 b0 = *(const float4*)(attW + i);
        float4 b1 = *(const float4*)(attW + i + 4);
        sum += b2f(a[0]) * b0.x + b2f(a[1]) * b0.y + b2f(a[2]) * b0.z + b2f(a[3]) * b0.w
             + b2f(a[4]) * b1.x + b2f(a[5]) * b1.y + b2f(a[6]) * b1.z + b2f(a[7]) * b1.w;
    }
    float sc = tanhf_(sum + attB[0]);
    float m = sc;
#pragma unroll
    for (int o = 32; o >= 1; o >>= 1) m = fmaxf(m, __shfl_xor(m, o, 64));
    if ((tid & 63) == 0) red[tid >> 6] = m;
    __syncthreads();
    m = fmaxf(fmaxf(red[0], red[1]), fmaxf(red[2], red[3]));
    float e = __expf(sc - m);
    float se = e;
#pragma unroll
    for (int o = 32; o >= 1; o >>= 1) se += __shfl_xor(se, o, 64);
    if ((tid & 63) == 0) red[4 + (tid >> 6)] = se;
    __syncthreads();
    se = red[4] + red[5] + red[6] + red[7];
    aw[tid] = e / se;
    __syncthreads();
    const int d = tid * 2;
    float a0 = 0.f, a1 = 0.f;
    for (int t2 = 0; t2 < 256; ++t2) {
        u32 v = *(const u32*)(sout + (long)t2 * 512 + d);
        float w = aw[t2];
        a0 += w * b2f((ushort_t)v);
        a1 += w * b2f((ushort_t)(v >> 16));
    }
    doc[d] = a0;
    doc[d + 1] = a1;
}

// ---------------------------------------------------------------------------
// Classifier + softmax -> d_out[10] fp32. 1 wave.
// ---------------------------------------------------------------------------
__global__ void classify(const float* __restrict__ doc, const float* __restrict__ clsW,
                         const float* __restrict__ clsB, float* __restrict__ outp)
{
    const int lane = threadIdx.x;
    float logit = -1e30f;
    if (lane < 10) {
        float s = clsB[lane];
        const float* wr = clsW + lane * 512;
        for (int i = 0; i < 512; ++i) s += doc[i] * wr[i];
        logit = s;
    }
    float m = logit;
#pragma unroll
    for (int o = 32; o >= 1; o >>= 1) m = fmaxf(m, __shfl_xor(m, o, 64));
    float e = (lane < 10) ? __expf(logit - m) : 0.f;
    float se = e;
#pragma unroll
    for (int o = 32; o >= 1; o >>= 1) se += __shfl_xor(se, o, 64);
    if (lane < 10) outp[lane] = e / se;
}

extern "C" void kernel_launch(void* const* d_in, const int* in_sizes, int n_in,
                              void* d_out, int out_size, void* d_ws, size_t ws_size,
                              hipStream_t stream)
{
    const int*   tokens = (const int*)d_in[0];
    const float* emb    = (const float*)d_in[1];
    const float* wWihF  = (const float*)d_in[2];
    const float* wWhhF  = (const float*)d_in[3];
    const float* wBihF  = (const float*)d_in[4];
    const float* wBhhF  = (const float*)d_in[5];
    const float* wWihB  = (const float*)d_in[6];
    const float* wWhhB  = (const float*)d_in[7];
    const float* wBihB  = (const float*)d_in[8];
    const float* wBhhB  = (const float*)d_in[9];
    const float* sWihF  = (const float*)d_in[10];
    const float* sWhhF  = (const float*)d_in[11];
    const float* sBihF  = (const float*)d_in[12];
    const float* sBhhF  = (const float*)d_in[13];
    const float* sWihB  = (const float*)d_in[14];
    const float* sWhhB  = (const float*)d_in[15];
    const float* sBihB  = (const float*)d_in[16];
    const float* sBhhB  = (const float*)d_in[17];
    const float* wAttW  = (const float*)d_in[18];
    const float* wAttB  = (const float*)d_in[19];
    const float* sAttW  = (const float*)d_in[20];
    const float* sAttB  = (const float*)d_in[21];
    const float* clsW   = (const float*)d_in[22];
    const float* clsB   = (const float*)d_in[23];

    char* ws = (char*)d_ws;
    ushort_t* xg   = (ushort_t*)(ws);              // [16384][1536] bf16  50,331,648 B
    ushort_t* wout = (ushort_t*)(ws + 50331648);   // [16384][512]  bf16  16,777,216 B
    float*    svec = (float*)(ws + 67108864);      // [256][512]    fp32     524,288 B
    ushort_t* sxg  = (ushort_t*)(ws + 67633152);   // [256][1536]   bf16     786,432 B
    ushort_t* sout = (ushort_t*)(ws + 68419584);   // [256][512]    bf16     262,144 B
    float*    doc  = (float*)(ws + 68681728);      // [512]         fp32       2,048 B

    // word level
    gemm_xg<<<dim3(12, 128), 256, 0, stream>>>(emb, tokens, wWihF, wWihB, wBihF, wBihB, xg, 256);
    gru_level<2, 8><<<256, 512, 0, stream>>>(wWhhF, wWhhB, wBhhF, wBhhB, xg, wout, 64);
    attn_word<<<256, 256, 0, stream>>>(wout, wAttW, wAttB, svec);
    // sentence level
    gemm_xg<<<dim3(12, 2), 256, 0, stream>>>(svec, nullptr, sWihF, sWihB, sBihF, sBihB, sxg, 512);
    gru_level<1, 16><<<2, 512, 0, stream>>>(sWhhF, sWhhB, sBhhF, sBhhB, sxg, sout, 256);
    attn_sent<<<1, 256, 0, stream>>>(sout, sAttW, sAttB, doc);
    classify<<<1, 64, 0, stream>>>(doc, clsW, clsB, (float*)d_out);
}